// Round 12
// baseline (338.384 us; speedup 1.0000x reference)
//
#include <hip/hip_runtime.h>
#include <hip/hip_bf16.h>
#include <cstdint>

// VQ quantizer: dist argmin over 8192 codes, gather, loss.
// R12: 3 waves/SIMD attempt — wave tile 64x64 (acc 64 AGPR), 256-thr blocks
// (tile 128x128), 3 blocks/CU via launch_bounds(256,3), 3x16KB LDS rotation,
// R11-style free-drift step: stage(t+2) -> 8 ds_read -> 12 MFMA -> WAITVM(4)
// -> barrier. Math core bitwise-identical to R5-R11.

typedef __bf16 bf16x8 __attribute__((ext_vector_type(8)));
typedef __bf16 bf16x4 __attribute__((ext_vector_type(4)));
typedef float  f32x16 __attribute__((ext_vector_type(16)));

#define N_ROWS  16384
#define N_CODES 8192
#define DDIM    256
#define NT      16             // 256 / BK16
#define BUFB    16384          // xh 4K | xl 4K | eh 4K | el 4K

#define STAGE16(gptr, lptr) __builtin_amdgcn_global_load_lds( \
    (const __attribute__((address_space(1))) void*)(gptr),    \
    (__attribute__((address_space(3))) void*)(lptr), 16, 0, 0)

#define SBAR() do { asm volatile("" ::: "memory"); \
                    __builtin_amdgcn_s_barrier();  \
                    asm volatile("" ::: "memory"); } while (0)
#define WAITVM(N) asm volatile("s_waitcnt vmcnt(" #N ")" ::: "memory")

// ---------- prep: split x (f32) into bf16 hi/lo planes ----------
__global__ void prep_x_k(const float* __restrict__ x,
                         __bf16* __restrict__ xhi, __bf16* __restrict__ xlo) {
  int i = blockIdx.x * 256 + threadIdx.x;
  float4 v = reinterpret_cast<const float4*>(x)[i];
  float a[4] = {v.x, v.y, v.z, v.w};
  bf16x4 h, l;
#pragma unroll
  for (int j = 0; j < 4; ++j) {
    __bf16 hh = (__bf16)a[j];
    h[j] = hh;
    l[j] = (__bf16)(a[j] - (float)hh);
  }
  reinterpret_cast<bf16x4*>(xhi)[i] = h;
  reinterpret_cast<bf16x4*>(xlo)[i] = l;
}

// ---------- prep: transpose emb [256][8192] -> [8192][256]; split + f32 copy ----------
__global__ void prep_e_k(const float* __restrict__ emb,
                         __bf16* __restrict__ ehi, __bf16* __restrict__ elo,
                         float* __restrict__ embT) {
  __shared__ float tile[64][65];
  const int kb = blockIdx.x * 64, db = blockIdx.y * 64;
  const int t = threadIdx.x;
  const int tk = t & 63, td = t >> 6;
#pragma unroll
  for (int c = 0; c < 16; ++c) {
    int d = c * 4 + td;
    tile[d][tk] = emb[(size_t)(db + d) * N_CODES + kb + tk];
  }
  __syncthreads();
#pragma unroll
  for (int c = 0; c < 16; ++c) {
    int k = c * 4 + td;
    int d = tk;
    float v = tile[d][k];
    size_t o = (size_t)(kb + k) * DDIM + db + d;
    __bf16 h = (__bf16)v;
    embT[o] = v;
    ehi[o] = h;
    elo[o] = (__bf16)(v - (float)h);
  }
}

// ---------- prep: ||e_k||^2 in exact f32 ----------
__global__ void enorm_k(const float* __restrict__ emb, float* __restrict__ enorm) {
  int k = blockIdx.x * 256 + threadIdx.x;
  float s = 0.f;
  for (int d = 0; d < DDIM; ++d) {
    float v = emb[(size_t)d * N_CODES + k];
    s += v * v;
  }
  enorm[k] = s;
}

// ---------- main: 128x128 tile, 4 waves (2rg x 2cg), 64x64/wave, BK=16 ----
// LDS buffer (16KB), 1KB units (64 lanes x 16B, one 32-row/code x 16-k frag):
//   [0,4K): xh units 0-3 | [4K,8K): xl | [8K,12K): eh | [12K,16K): el
// Wave w stages {xh[w], xl[w], eh[w], el[w]} of step t+2 per step.
// 3-buffer rotation: write buf (t+2)%3 (last read t-1, retired); WAITVM(4)
// at step end retires t+1's 4 loads (issued at t-1, ~1 step old); 1 barrier.
// A-operand = e-frag (code=lane&31, k-half=lane>>5), B-operand = x-frag.
// C layout (m74): col(lane&31)=xrow, code=(reg&3)+8*(reg>>2)+4*(lane>>5).
__global__ __launch_bounds__(256, 3) void vq_main_k(
    const __bf16* __restrict__ xhi, const __bf16* __restrict__ xlo,
    const __bf16* __restrict__ ehi, const __bf16* __restrict__ elo,
    const float* __restrict__ enorm, unsigned long long* __restrict__ keys) {
  __shared__ alignas(16) unsigned char smem[3][BUFB];     // 48KB -> 3 blocks/CU

  const int tid = threadIdx.x;
  const int wid = tid >> 6, lane = tid & 63;
  const int cg = wid & 1, rg = wid >> 1;      // code-half(64), row-half(64)
  const int l31 = lane & 31, lh = lane >> 5;

  // XCD swizzle: each XCD owns a 16-bm window (2048 rows, 2MB, L2-resident)
  // swept over all 64 bn panels. 8192 % 8 == 0 -> bijective.
  const int orig = blockIdx.x;
  const int j = orig >> 3;
  const int bm = (orig & 7) * 16 + (j & 15);  // 0..127
  const int bn = j >> 4;                      // 0..63

  // acc init = -||e||^2/2  (argmin dist == argmax(dot - en/2))
  const int cbase = bn * 128 + cg * 64 + lh * 4;
  f32x16 acc[2][2];
#pragma unroll
  for (int c = 0; c < 2; ++c) {
    f32x16 ci;
#pragma unroll
    for (int q = 0; q < 4; ++q)
#pragma unroll
      for (int r = 0; r < 4; ++r)
        ci[q * 4 + r] = -0.5f * enorm[cbase + c * 32 + q * 8 + r];
    acc[c][0] = ci; acc[c][1] = ci;
  }
  __builtin_amdgcn_sched_barrier(0);   // enorm vmem retires before staging

  // staging sources (wave-owned row/code unit = wid; 32 rows/codes each)
  const size_t aoff = (size_t)(bm * 128 + wid * 32 + l31) * 512 + (size_t)lh * 16;
  const size_t boff = (size_t)(bn * 128 + wid * 32 + l31) * 512 + (size_t)lh * 16;
  const char* pxh = (const char*)xhi + aoff;
  const char* pxl = (const char*)xlo + aoff;
  const char* peh = (const char*)ehi + boff;
  const char* pel = (const char*)elo + boff;
  const int dxh = wid * 1024, dxl = 4096 + wid * 1024;
  const int deh = 8192 + wid * 1024, del = 12288 + wid * 1024;

  // fragment read offsets (lane-linear)
  const int xrd = rg * 2048 + lane * 16;          // + r*1024 ; xl at +4096
  const int erd = 8192 + cg * 2048 + lane * 16;   // + c*1024 ; el at +4096

  // prologue: stage steps 0,1 -> buffers 0,1 (4 loads each per wave)
#pragma unroll
  for (int s = 0; s < 2; ++s) {
    unsigned char* bs = smem[s];
    STAGE16(pxh + s * 32, bs + dxh);
    STAGE16(pxl + s * 32, bs + dxl);
    STAGE16(peh + s * 32, bs + deh);
    STAGE16(pel + s * 32, bs + del);
  }
  WAITVM(4);         // step 0's 4 landed; step 1's in flight
  SBAR();

#pragma unroll 1
  for (int t = 0; t < NT; ++t) {
    int s = t + 2; if (s >= NT) s -= NT;     // wrap: writes land in dead buffers
    const unsigned char* rb = smem[t % 3];
    unsigned char* wb = smem[(t + 2) % 3];
    const size_t kb = (size_t)s * 32;

    // stage first (latency hides under this step's compute)
    STAGE16(pxh + kb, wb + dxh);
    STAGE16(pxl + kb, wb + dxl);
    STAGE16(peh + kb, wb + deh);
    STAGE16(pel + kb, wb + del);

    // reads + 12 MFMA: compiler interleaves with fine-grained lgkmcnt;
    // waves drift (no intra-step barrier), 3 waves/SIMD cover latency.
    bf16x8 ehf[2], elf[2], xhf[2], xlf[2];
#pragma unroll
    for (int c = 0; c < 2; ++c) ehf[c] = *(const bf16x8*)(rb + erd + c * 1024);
#pragma unroll
    for (int r = 0; r < 2; ++r) xhf[r] = *(const bf16x8*)(rb + xrd + r * 1024);
#pragma unroll
    for (int r = 0; r < 2; ++r) xlf[r] = *(const bf16x8*)(rb + 4096 + xrd + r * 1024);
#pragma unroll
    for (int c = 0; c < 2; ++c) elf[c] = *(const bf16x8*)(rb + 4096 + erd + c * 1024);

    __builtin_amdgcn_s_setprio(1);
#pragma unroll
    for (int c = 0; c < 2; ++c)
#pragma unroll
      for (int r = 0; r < 2; ++r)
        acc[c][r] = __builtin_amdgcn_mfma_f32_32x32x16_bf16(ehf[c], xhf[r], acc[c][r], 0, 0, 0);
#pragma unroll
    for (int c = 0; c < 2; ++c)
#pragma unroll
      for (int r = 0; r < 2; ++r)
        acc[c][r] = __builtin_amdgcn_mfma_f32_32x32x16_bf16(ehf[c], xlf[r], acc[c][r], 0, 0, 0);
#pragma unroll
    for (int c = 0; c < 2; ++c)
#pragma unroll
      for (int r = 0; r < 2; ++r)
        acc[c][r] = __builtin_amdgcn_mfma_f32_32x32x16_bf16(elf[c], xhf[r], acc[c][r], 0, 0, 0);
    __builtin_amdgcn_s_setprio(0);

    WAITVM(4);       // t+1's 4 loads (issued at t-1) retired; t+2's in flight
    SBAR();
  }
  WAITVM(0);         // drain wrapped tail stages

  // epilogue: per lane, xrow = bm*128 + rg*64 + r*32 + l31 holds 64 scores
  // (2 code-frags x 32). Ascending-code scan, strict > -> smallest code on tie.
#pragma unroll
  for (int r = 0; r < 2; ++r) {
    float bv = -3.4e38f;
    unsigned bcode = 0;
#pragma unroll
    for (int c = 0; c < 2; ++c)
#pragma unroll
      for (int q = 0; q < 4; ++q)
#pragma unroll
        for (int rr = 0; rr < 4; ++rr) {
          float v = acc[c][r][q * 4 + rr];
          unsigned cd = (unsigned)(cbase + c * 32 + q * 8 + rr);
          if (v > bv) { bv = v; bcode = cd; }
        }
    unsigned u = __float_as_uint(bv);
    u = (u & 0x80000000u) ? ~u : (u | 0x80000000u);        // order-preserving
    unsigned long long key =
        ((unsigned long long)u << 32) | (unsigned)(0xFFFFFFFFu ^ bcode);
    unsigned olo = __shfl_xor((unsigned)key, 32, 64);
    unsigned ohi = __shfl_xor((unsigned)(key >> 32), 32, 64);
    unsigned long long okey = ((unsigned long long)ohi << 32) | olo;
    if (okey > key) key = okey;
    if (lane < 32)
      atomicMax(&keys[bm * 128 + rg * 64 + r * 32 + l31], key);
  }
}

// ---------- gather q (exact f32), q_st out, per-row squared error ----------
__global__ void gather_k(const float* __restrict__ x, const float* __restrict__ embT,
                         const unsigned long long* __restrict__ keys,
                         float* __restrict__ qout, float* __restrict__ rowsum) {
  const int row = blockIdx.x;
  const int lane = threadIdx.x;
  const unsigned low = (unsigned)(keys[row] & 0xffffffffull);
  const int idx = (int)(~low);                 // stored 0xFFFFFFFF ^ code
  float4 q  = reinterpret_cast<const float4*>(embT + (size_t)idx * DDIM)[lane];
  float4 xv = reinterpret_cast<const float4*>(x + (size_t)row * DDIM)[lane];
  reinterpret_cast<float4*>(qout + (size_t)row * DDIM)[lane] = q;
  float dx = q.x - xv.x, dy = q.y - xv.y, dz = q.z - xv.z, dw = q.w - xv.w;
  float s = dx * dx + dy * dy + dz * dz + dw * dw;
#pragma unroll
  for (int mk = 32; mk; mk >>= 1) s += __shfl_xor(s, mk, 64);
  if (lane == 0) rowsum[row] = s;
}

// ---------- deterministic final loss reduce ----------
__global__ void loss_k(const float* __restrict__ rowsum, float* __restrict__ out) {
  __shared__ float sm[4];
  const int t = threadIdx.x;
  float s = 0.f;
  for (int j = t; j < N_ROWS; j += 256) s += rowsum[j];
#pragma unroll
  for (int mk = 32; mk; mk >>= 1) s += __shfl_xor(s, mk, 64);
  if ((t & 63) == 0) sm[t >> 6] = s;
  __syncthreads();
  if (t == 0) out[0] = 2.0f * (sm[0] + sm[1] + sm[2] + sm[3]) / (float)(N_ROWS * DDIM);
}

extern "C" void kernel_launch(void* const* d_in, const int* in_sizes, int n_in,
                              void* d_out, int out_size, void* d_ws, size_t ws_size,
                              hipStream_t stream) {
  const float* x   = (const float*)d_in[0];          // [16,1024,256] f32
  const float* emb = (const float*)d_in[1];          // [256,8192] f32
  float* qout = (float*)d_out;                       // 4,194,304 q_st + 1 loss

  char* w = (char*)d_ws;
  unsigned long long* keys = (unsigned long long*)w;                 // 128 KB
  float* rowsum = (float*)(w + 131072);                              // 64 KB
  __bf16* xhi = (__bf16*)(w + 196608);                               // 8 MB
  __bf16* xlo = xhi + (size_t)N_ROWS * DDIM;                         // 8 MB
  __bf16* ehi = xlo + (size_t)N_ROWS * DDIM;                         // 4 MB
  __bf16* elo = ehi + (size_t)N_CODES * DDIM;                        // 4 MB
  float*  embT = (float*)(elo + (size_t)N_CODES * DDIM);             // 8 MB
  float*  enorm = embT + (size_t)N_CODES * DDIM;                     // 32 KB

  hipMemsetAsync(keys, 0, N_ROWS * sizeof(unsigned long long), stream);  // atomicMax
  prep_x_k<<<4096, 256, 0, stream>>>(x, xhi, xlo);
  prep_e_k<<<dim3(N_CODES / 64, DDIM / 64), 256, 0, stream>>>(emb, ehi, elo, embT);
  enorm_k<<<N_CODES / 256, 256, 0, stream>>>(emb, enorm);
  vq_main_k<<<8192, 256, 0, stream>>>(xhi, xlo, ehi, elo, enorm, keys);
  gather_k<<<N_ROWS, 64, 0, stream>>>(x, embT, keys, qout, rowsum);
  loss_k<<<1, 256, 0, stream>>>(rowsum, qout + (size_t)N_ROWS * DDIM);
}